// Round 7
// baseline (288.033 us; speedup 1.0000x reference)
//
#include <hip/hip_runtime.h>

// ---------------------------------------------------------------------------
// out[n] = x_n^T A x_n / (x_n^T x_n),  A = Re(U^H Z U), U = full circuit unitary
// Kernel 1: simulate circuit on 128 basis columns -> U (complex fp32) in ws
// Kernel 2: A_ij = sum_k z_k (Ur_ki Ur_kj + Ui_ki Ui_kj) -> bf16 A in ws
// Kernel 3: bf16 MFMA GEMM y = A x fused with dot/norm epilogue
//
// R6 -> R7: Little's-law redesign. R6 (2 blocks x 2 waves/CU, DMA + vmcnt(0)
// + barrier each iter) could only sustain ~4-5 KB in flight per CU -> ~2.2
// TB/s. Now: NO barriers in the loop, no DMA; 4-wave blocks free-running at
// 3-4 blocks/CU (12-16 waves/CU), each wave streaming 8 independent dwordx4
// per iter straight into registers (transient, packed immediately -> no
// held-fp32 spill risk). Epilogue x re-read issued after the MFMAs from
// L1/L2 (per-XCD working set ~3 MB < 4 MB L2 -> no extra HBM fetch).
// A stays in LDS with the proven 0-conflict XOR-chunk swizzle.
// ---------------------------------------------------------------------------

#define N_QUBITS 7
#define DIM 128
#define N_LAYERS 4
#define BATCH 262144
#define GRID 1024
#define WAVES_TOT (GRID * 4)                    // 4096 waves
#define WITERS (BATCH / 16 / WAVES_TOT)         // 4 iters per wave

typedef short short8 __attribute__((ext_vector_type(8)));
typedef float f32x4 __attribute__((ext_vector_type(4)));

__device__ __forceinline__ unsigned short f2bf(float f) {
  unsigned u = __builtin_bit_cast(unsigned, f);
  u += 0x7fffu + ((u >> 16) & 1u);   // RNE
  return (unsigned short)(u >> 16);
}

// [bf16(x) | bf16(y)<<16]: round-half-up add + v_perm byte select
__device__ __forceinline__ unsigned pk2(float x, float y) {
  unsigned ux = __builtin_bit_cast(unsigned, x) + 0x8000u;
  unsigned uy = __builtin_bit_cast(unsigned, y) + 0x8000u;
  return __builtin_amdgcn_perm(uy, ux, 0x07060302u);
}

__device__ __forceinline__ short8 pack_bf16(float4 lo, float4 hi) {
  uint4 d;
  d.x = pk2(lo.x, lo.y);
  d.y = pk2(lo.z, lo.w);
  d.z = pk2(hi.x, hi.y);
  d.w = pk2(hi.z, hi.w);
  return __builtin_bit_cast(short8, d);
}

// ---------------------------------------------------------------------------
// Kernel 1: one block (64 threads) per column c. State (128 complex) in LDS.
// Qubit w <-> bit (6-w) of the flattened index.
// ---------------------------------------------------------------------------
__global__ void sim_columns(const float* __restrict__ W,
                            float* __restrict__ Ur, float* __restrict__ Ui) {
  __shared__ float sr[DIM], si[DIM];
  const int c = blockIdx.x;
  const int t = threadIdx.x;  // 0..63

  sr[t] = (t == c) ? 1.f : 0.f;        si[t] = 0.f;
  sr[t + 64] = (t + 64 == c) ? 1.f : 0.f;  si[t + 64] = 0.f;
  __syncthreads();

  for (int l = 0; l < N_LAYERS; ++l) {
    for (int w = 0; w < N_QUBITS; ++w) {
      const float phi = W[(l * 7 + w) * 3 + 0];
      const float th  = W[(l * 7 + w) * 3 + 1];
      const float om  = W[(l * 7 + w) * 3 + 2];
      const float ch = __cosf(0.5f * th), sh = __sinf(0.5f * th);
      const float ap = 0.5f * (phi + om), am = 0.5f * (phi - om);
      const float cap = __cosf(ap), sap = __sinf(ap);
      const float cam = __cosf(am), sam = __sinf(am);
      const float ar =  cap * ch, ai = -sap * ch;
      const float br = -cam * sh, bi = -sam * sh;
      const float cr =  cam * sh, ci = -sam * sh;
      const float dr =  cap * ch, di =  sap * ch;

      const int m = 1 << (6 - w);
      const int i0 = ((t & ~(m - 1)) << 1) | (t & (m - 1));
      const int i1 = i0 | m;
      const float x0r = sr[i0], x0i = si[i0];
      const float x1r = sr[i1], x1i = si[i1];
      __syncthreads();
      sr[i0] = ar * x0r - ai * x0i + br * x1r - bi * x1i;
      si[i0] = ar * x0i + ai * x0r + br * x1i + bi * x1r;
      sr[i1] = cr * x0r - ci * x0i + dr * x1r - di * x1i;
      si[i1] = cr * x0i + ci * x0r + dr * x1i + di * x1r;
      __syncthreads();
    }
    const int r = (l % (N_QUBITS - 1)) + 1;  // ranges [1,2,3,4]
    for (int w = 0; w < N_QUBITS; ++w) {
      const int ctrl = w, tgt = (w + r) % N_QUBITS;
      const int cmask = 1 << (6 - ctrl), tmask = 1 << (6 - tgt);
      const int i0 = ((t & ~(tmask - 1)) << 1) | (t & (tmask - 1));
      const int i1 = i0 | tmask;
      const float a0r = sr[i0], a0i = si[i0];
      const float a1r = sr[i1], a1i = si[i1];
      __syncthreads();
      if (i0 & cmask) {
        sr[i0] = a1r; si[i0] = a1i;
        sr[i1] = a0r; si[i1] = a0i;
      }
      __syncthreads();
    }
  }
  Ur[(size_t)t * DIM + c]        = sr[t];
  Ui[(size_t)t * DIM + c]        = si[t];
  Ur[(size_t)(t + 64) * DIM + c] = sr[t + 64];
  Ui[(size_t)(t + 64) * DIM + c] = si[t + 64];
}

// ---------------------------------------------------------------------------
// Kernel 2: A_ij, identity k-layout. 128 blocks (row i) x 128 threads (j).
// Ur[k][i] broadcasts; Ur[k][j] coalesces; all L2-hot.
// ---------------------------------------------------------------------------
__global__ void build_A(const float* __restrict__ Ur, const float* __restrict__ Ui,
                        unsigned short* __restrict__ Ab) {
  const int i = blockIdx.x;
  const int j = threadIdx.x;
  float s = 0.f;
#pragma unroll 8
  for (int k = 0; k < DIM; ++k) {
    const float zk = (((k >> 6) ^ k) & 1) ? -1.f : 1.f;
    s += zk * (Ur[k * DIM + i] * Ur[k * DIM + j] + Ui[k * DIM + i] * Ui[k * DIM + j]);
  }
  Ab[i * DIM + j] = f2bf(s);
}

// ---------------------------------------------------------------------------
// Kernel 3. Block = 4 waves, one barrier total (after A-fill); waves then
// free-run. Each wave-iter handles 16 batch rows.
//   A-frag: lane holds Ab[m = 16t + n16][k = 32kt + 8g + j]  (LDS, swizzled:
//           row m chunk c stored at slot c ^ (m & 15); 2-way = free, 0
//           conflicts measured in R2)
//   B-frag: lane (g,n16): row R = tile*16+n16, cols 32kt+8g..+7 (2 dwordx4)
//   C/D:    acc[t][r] = y[16t + 4g + r][n16]
// nrm accumulated from the fp32 load values at load time; epilogue xe
// re-read (cols 16t+4g..+3, same 512B row) AFTER the MFMAs, transient regs.
// ---------------------------------------------------------------------------
__global__ __launch_bounds__(256, 3) void vqa_main(const float* __restrict__ X,
                                                   const unsigned short* __restrict__ Ab,
                                                   float* __restrict__ out) {
  __shared__ unsigned short As[DIM * DIM];   // 32 KB

  const int tid = threadIdx.x;
  const int lane = tid & 63;
  const int wave = tid >> 6;
  const int n16 = lane & 15;
  const int g = lane >> 4;

  // fill A into LDS with chunk swizzle (source L2/L3-hot)
#pragma unroll
  for (int i = 0; i < 8; ++i) {
    const int q = tid + 256 * i;          // 16B-chunk id, 0..2047
    const int m = q >> 4, c = q & 15;
    const short8 v = *reinterpret_cast<const short8*>(Ab + q * 8);
    *reinterpret_cast<short8*>(As + m * DIM + ((c ^ (m & 15)) << 3)) = v;
  }
  __syncthreads();   // the only barrier; As is read-only below

  const unsigned short* abase[4];
#pragma unroll
  for (int kt = 0; kt < 4; ++kt)
    abase[kt] = As + n16 * DIM + (((4 * kt + g) ^ n16) << 3);

  const int wid = blockIdx.x * 4 + wave;

#pragma unroll 1
  for (int it = 0; it < WITERS; ++it) {
    const int row = (wid + it * WAVES_TOT) * 16 + n16;
    const float* xp = X + (size_t)row * DIM;

    // B-fragments: 8 independent dwordx4; nrm from the fp32 values in flight
    short8 bfrag[4];
    float nrm = 0.f;
#pragma unroll
    for (int kt = 0; kt < 4; ++kt) {
      const float4 lo = *reinterpret_cast<const float4*>(xp + kt * 32 + g * 8);
      const float4 hi = *reinterpret_cast<const float4*>(xp + kt * 32 + g * 8 + 4);
      nrm += lo.x * lo.x + lo.y * lo.y + lo.z * lo.z + lo.w * lo.w;
      nrm += hi.x * hi.x + hi.y * hi.y + hi.z * hi.z + hi.w * hi.w;
      bfrag[kt] = pack_bf16(lo, hi);
    }

    f32x4 acc[8];
#pragma unroll
    for (int t = 0; t < 8; ++t) acc[t] = (f32x4){0.f, 0.f, 0.f, 0.f};
#pragma unroll
    for (int kt = 0; kt < 4; ++kt) {
#pragma unroll
      for (int t = 0; t < 8; ++t) {
        const short8 af = *reinterpret_cast<const short8*>(abase[kt] + t * 16 * DIM);
        acc[t] = __builtin_amdgcn_mfma_f32_16x16x32_bf16(af, bfrag[kt], acc[t], 0, 0, 0);
      }
    }

    // epilogue: re-read same row from L1/L2 (transient), dot, reduce, store
    float dot = 0.f;
#pragma unroll
    for (int t = 0; t < 8; ++t) {
      const float4 xe = *reinterpret_cast<const float4*>(xp + t * 16 + g * 4);
      dot += xe.x * acc[t][0] + xe.y * acc[t][1] + xe.z * acc[t][2] + xe.w * acc[t][3];
    }
    dot += __shfl_xor(dot, 16, 64);
    dot += __shfl_xor(dot, 32, 64);
    nrm += __shfl_xor(nrm, 16, 64);
    nrm += __shfl_xor(nrm, 32, 64);
    if (lane < 16) out[row] = dot / nrm;   // g==0 lanes: 16 consecutive floats
  }
}

// ---------------------------------------------------------------------------
extern "C" void kernel_launch(void* const* d_in, const int* in_sizes, int n_in,
                              void* d_out, int out_size, void* d_ws, size_t ws_size,
                              hipStream_t stream) {
  const float* X = (const float*)d_in[0];   // (262144, 128) fp32
  const float* W = (const float*)d_in[1];   // (4, 7, 3) fp32
  float* out = (float*)d_out;               // (262144,) fp32

  float* Ur = (float*)d_ws;
  float* Ui = Ur + DIM * DIM;
  unsigned short* Ab = (unsigned short*)(Ui + DIM * DIM);

  sim_columns<<<DIM, 64, 0, stream>>>(W, Ur, Ui);
  build_A<<<DIM, DIM, 0, stream>>>(Ur, Ui, Ab);
  vqa_main<<<GRID, 256, 0, stream>>>(X, Ab, out);
}

// Round 8
// 266.718 us; speedup vs baseline: 1.0799x; 1.0799x over previous
//
#include <hip/hip_runtime.h>

// ---------------------------------------------------------------------------
// out[n] = x_n^T A x_n / (x_n^T x_n),  A = Re(U^H Z U), U = full circuit unitary
// Kernel 1: simulate circuit on 128 basis columns -> U (complex fp32) in ws
// Kernel 2: A_ij -> bf16, k-columns PERMUTED by pi (baked in)
// Kernel 3: bf16 MFMA GEMM y = A x fused with dot/norm epilogue
//
// R7 -> R8: kill the epilogue re-read, kill the spill. R2/R4/R7 all show the
// same scratch signature (WRITE_SIZE 66-121 MB) whenever a post-MFMA x
// re-read exists: the scheduler hoists those 8 loads into the MFMA section,
// manufactures 32 live regs, and spills 16 dwords/lane/iter. Fix: pi-permuted
// A k-layout makes each lane's B-fragment values exactly the x elements its
// C/D accumulators need -> dot computed by UNPACKING bfrag (bf16->fp32 =
// shift/mask), zero memory ops after the MFMAs. nrm from exact fp32 at load.
// Free-running 4-wave blocks (one barrier total), A in LDS, 0-conflict
// XOR-chunk swizzle (measured R2/R7).
// ---------------------------------------------------------------------------

#define N_QUBITS 7
#define DIM 128
#define N_LAYERS 4
#define BATCH 262144
#define GRID 1024
#define WAVES_TOT (GRID * 4)                    // 4096 waves
#define WITERS (BATCH / 16 / WAVES_TOT)         // 4 iters per wave

typedef short short8 __attribute__((ext_vector_type(8)));
typedef float f32x4 __attribute__((ext_vector_type(4)));

__device__ __forceinline__ unsigned short f2bf(float f) {
  unsigned u = __builtin_bit_cast(unsigned, f);
  u += 0x7fffu + ((u >> 16) & 1u);   // RNE
  return (unsigned short)(u >> 16);
}

// [bf16(x) | bf16(y)<<16]: round-half-up add + v_perm byte select
__device__ __forceinline__ unsigned pk2(float x, float y) {
  unsigned ux = __builtin_bit_cast(unsigned, x) + 0x8000u;
  unsigned uy = __builtin_bit_cast(unsigned, y) + 0x8000u;
  return __builtin_amdgcn_perm(uy, ux, 0x07060302u);
}

__device__ __forceinline__ short8 pack_bf16(float4 lo, float4 hi) {
  uint4 d;
  d.x = pk2(lo.x, lo.y);
  d.y = pk2(lo.z, lo.w);
  d.z = pk2(hi.x, hi.y);
  d.w = pk2(hi.z, hi.w);
  return __builtin_bit_cast(short8, d);
}

__device__ __forceinline__ float bf_lo(unsigned u) {   // float of packed low bf16
  return __builtin_bit_cast(float, u << 16);
}
__device__ __forceinline__ float bf_hi(unsigned u) {   // float of packed high bf16
  return __builtin_bit_cast(float, u & 0xffff0000u);
}

// ---------------------------------------------------------------------------
// Kernel 1: one block (64 threads) per column c. State (128 complex) in LDS.
// Qubit w <-> bit (6-w) of the flattened index.
// ---------------------------------------------------------------------------
__global__ void sim_columns(const float* __restrict__ W,
                            float* __restrict__ Ur, float* __restrict__ Ui) {
  __shared__ float sr[DIM], si[DIM];
  const int c = blockIdx.x;
  const int t = threadIdx.x;  // 0..63

  sr[t] = (t == c) ? 1.f : 0.f;        si[t] = 0.f;
  sr[t + 64] = (t + 64 == c) ? 1.f : 0.f;  si[t + 64] = 0.f;
  __syncthreads();

  for (int l = 0; l < N_LAYERS; ++l) {
    for (int w = 0; w < N_QUBITS; ++w) {
      const float phi = W[(l * 7 + w) * 3 + 0];
      const float th  = W[(l * 7 + w) * 3 + 1];
      const float om  = W[(l * 7 + w) * 3 + 2];
      const float ch = __cosf(0.5f * th), sh = __sinf(0.5f * th);
      const float ap = 0.5f * (phi + om), am = 0.5f * (phi - om);
      const float cap = __cosf(ap), sap = __sinf(ap);
      const float cam = __cosf(am), sam = __sinf(am);
      const float ar =  cap * ch, ai = -sap * ch;
      const float br = -cam * sh, bi = -sam * sh;
      const float cr =  cam * sh, ci = -sam * sh;
      const float dr =  cap * ch, di =  sap * ch;

      const int m = 1 << (6 - w);
      const int i0 = ((t & ~(m - 1)) << 1) | (t & (m - 1));
      const int i1 = i0 | m;
      const float x0r = sr[i0], x0i = si[i0];
      const float x1r = sr[i1], x1i = si[i1];
      __syncthreads();
      sr[i0] = ar * x0r - ai * x0i + br * x1r - bi * x1i;
      si[i0] = ar * x0i + ai * x0r + br * x1i + bi * x1r;
      sr[i1] = cr * x0r - ci * x0i + dr * x1r - di * x1i;
      si[i1] = cr * x0i + ci * x0r + dr * x1i + di * x1r;
      __syncthreads();
    }
    const int r = (l % (N_QUBITS - 1)) + 1;  // ranges [1,2,3,4]
    for (int w = 0; w < N_QUBITS; ++w) {
      const int ctrl = w, tgt = (w + r) % N_QUBITS;
      const int cmask = 1 << (6 - ctrl), tmask = 1 << (6 - tgt);
      const int i0 = ((t & ~(tmask - 1)) << 1) | (t & (tmask - 1));
      const int i1 = i0 | tmask;
      const float a0r = sr[i0], a0i = si[i0];
      const float a1r = sr[i1], a1i = si[i1];
      __syncthreads();
      if (i0 & cmask) {
        sr[i0] = a1r; si[i0] = a1i;
        sr[i1] = a0r; si[i1] = a0i;
      }
      __syncthreads();
    }
  }
  Ur[(size_t)t * DIM + c]        = sr[t];
  Ui[(size_t)t * DIM + c]        = si[t];
  Ur[(size_t)(t + 64) * DIM + c] = sr[t + 64];
  Ui[(size_t)(t + 64) * DIM + c] = si[t + 64];
}

// ---------------------------------------------------------------------------
// Kernel 2: Ab[i][k'] = f2bf( sum_k z_k (Ur[k][i]Ur[k][p] + Ui[k][i]Ui[k][p]) )
// with p = pi(k'):  k' bits [6:5]=kt [4:3]=g [2]=j2 [1:0]=j10
//                   p = 32 kt + 16 j2 + 4 g + j10
// 128 blocks (row i) x 128 threads (k'). Ur[k][i] broadcasts; Ur[k][p]
// stays within the 512B row; all L2-hot.
// ---------------------------------------------------------------------------
__global__ void build_A(const float* __restrict__ Ur, const float* __restrict__ Ui,
                        unsigned short* __restrict__ Ab) {
  const int i = blockIdx.x;
  const int kp = threadIdx.x;
  const int p = (kp & 0x60) | ((kp & 0x04) << 2) | ((kp & 0x18) >> 1) | (kp & 0x03);
  float s = 0.f;
#pragma unroll 8
  for (int k = 0; k < DIM; ++k) {
    const float zk = (((k >> 6) ^ k) & 1) ? -1.f : 1.f;
    s += zk * (Ur[k * DIM + i] * Ur[k * DIM + p] + Ui[k * DIM + i] * Ui[k * DIM + p]);
  }
  Ab[i * DIM + kp] = f2bf(s);
}

// ---------------------------------------------------------------------------
// Kernel 3. Block = 4 waves, one barrier total (after A-fill); free-running.
// Each wave-iter handles 16 batch rows.
//   A-frag: lane holds Ab[m = 16t + n16][k' = 32kt + 8g + j]  (pi-space, LDS
//           XOR-chunk swizzled: row m chunk c at slot c ^ (m&15); 0 conflicts)
//   B-frag: lane (g,n16), row n: lo = x[n][32kt+4g..+3], hi = x[n][32kt+16+4g..+3]
//           packed in j order (lo then hi) == pi's column order
//   C/D:    acc[t][r] = y[16t + 4g + r][n16]
// Epilogue: dot = sum over lane's pairs bf16(x) * acc  -- bfrag UNPACK, no
// memory ops after the MFMAs (the R2/R4/R7 spill trigger). nrm from exact
// fp32 at load time.
// ---------------------------------------------------------------------------
__global__ __launch_bounds__(256, 3) void vqa_main(const float* __restrict__ X,
                                                   const unsigned short* __restrict__ Ab,
                                                   float* __restrict__ out) {
  __shared__ unsigned short As[DIM * DIM];   // 32 KB

  const int tid = threadIdx.x;
  const int lane = tid & 63;
  const int wave = tid >> 6;
  const int n16 = lane & 15;
  const int g = lane >> 4;

  // fill A into LDS with chunk swizzle (source L2/L3-hot)
#pragma unroll
  for (int i = 0; i < 8; ++i) {
    const int q = tid + 256 * i;          // 16B-chunk id, 0..2047
    const int m = q >> 4, c = q & 15;
    const short8 v = *reinterpret_cast<const short8*>(Ab + q * 8);
    *reinterpret_cast<short8*>(As + m * DIM + ((c ^ (m & 15)) << 3)) = v;
  }
  __syncthreads();   // the only barrier; As is read-only below

  const unsigned short* abase[4];
#pragma unroll
  for (int kt = 0; kt < 4; ++kt)
    abase[kt] = As + n16 * DIM + (((4 * kt + g) ^ n16) << 3);

  const int wid = blockIdx.x * 4 + wave;

#pragma unroll 1
  for (int it = 0; it < WITERS; ++it) {
    const int row = (wid + it * WAVES_TOT) * 16 + n16;
    const float* xp = X + (size_t)row * DIM + g * 4;

    // B-fragments: 8 independent dwordx4 (pi column order); nrm in flight
    short8 bfrag[4];
    float nrm = 0.f;
#pragma unroll
    for (int kt = 0; kt < 4; ++kt) {
      const float4 lo = *reinterpret_cast<const float4*>(xp + kt * 32);
      const float4 hi = *reinterpret_cast<const float4*>(xp + kt * 32 + 16);
      nrm += lo.x * lo.x + lo.y * lo.y + lo.z * lo.z + lo.w * lo.w;
      nrm += hi.x * hi.x + hi.y * hi.y + hi.z * hi.z + hi.w * hi.w;
      bfrag[kt] = pack_bf16(lo, hi);
    }

    f32x4 acc[8];
#pragma unroll
    for (int t = 0; t < 8; ++t) acc[t] = (f32x4){0.f, 0.f, 0.f, 0.f};
#pragma unroll
    for (int kt = 0; kt < 4; ++kt) {
#pragma unroll
      for (int t = 0; t < 8; ++t) {
        const short8 af = *reinterpret_cast<const short8*>(abase[kt] + t * 16 * DIM);
        acc[t] = __builtin_amdgcn_mfma_f32_16x16x32_bf16(af, bfrag[kt], acc[t], 0, 0, 0);
      }
    }

    // epilogue: dot from UNPACKED bfrag (no memory ops) --
    // lo pair r <-> acc[2kt][r], hi pair r <-> acc[2kt+1][r]
    float dot = 0.f;
#pragma unroll
    for (int kt = 0; kt < 4; ++kt) {
      const uint4 u = __builtin_bit_cast(uint4, bfrag[kt]);
      const f32x4 ae = acc[2 * kt], ao = acc[2 * kt + 1];
      dot += bf_lo(u.x) * ae[0] + bf_hi(u.x) * ae[1];
      dot += bf_lo(u.y) * ae[2] + bf_hi(u.y) * ae[3];
      dot += bf_lo(u.z) * ao[0] + bf_hi(u.z) * ao[1];
      dot += bf_lo(u.w) * ao[2] + bf_hi(u.w) * ao[3];
    }
    dot += __shfl_xor(dot, 16, 64);
    dot += __shfl_xor(dot, 32, 64);
    nrm += __shfl_xor(nrm, 16, 64);
    nrm += __shfl_xor(nrm, 32, 64);
    if (lane < 16) out[row] = dot / nrm;   // g==0 lanes: 16 consecutive floats
  }
}

// ---------------------------------------------------------------------------
extern "C" void kernel_launch(void* const* d_in, const int* in_sizes, int n_in,
                              void* d_out, int out_size, void* d_ws, size_t ws_size,
                              hipStream_t stream) {
  const float* X = (const float*)d_in[0];   // (262144, 128) fp32
  const float* W = (const float*)d_in[1];   // (4, 7, 3) fp32
  float* out = (float*)d_out;               // (262144,) fp32

  float* Ur = (float*)d_ws;
  float* Ui = Ur + DIM * DIM;
  unsigned short* Ab = (unsigned short*)(Ui + DIM * DIM);

  sim_columns<<<DIM, 64, 0, stream>>>(W, Ur, Ui);
  build_A<<<DIM, DIM, 0, stream>>>(Ur, Ui, Ab);
  vqa_main<<<GRID, 256, 0, stream>>>(X, Ab, out);
}